// Round 8
// baseline (135.619 us; speedup 1.0000x reference)
//
#include <hip/hip_runtime.h>
#include <hip/hip_bf16.h>

// MemoryEfficientAttention round 8: round-7 interleave, spill fixed.
//  - __launch_bounds__(512, 1): second arg is min BLOCKS/CU (CUDA semantics);
//    (512,2) forced a 128-VGPR cap -> the interleave's ~170 live VGPRs spilled
//    to scratch (round 7: WRITE_SIZE +18MB, 139us). LDS (97KB) already limits
//    to 1 block/CU, so (512,1) loses nothing and raises the cap to 256.
//  - BODY(t): QK(t+1) -> 4 chunks of {4 PV-MFMA(t) + exp2/pack slice(t+1)}:
//    matrix pipe + LDS pipe + VALU/TRANS co-issue.
//  - defer-max: common path never touches mrun/oacc -> interleave is safe.
//  - swapped-QK 32x32, triple-buffered LDS K/V, permlane32_swap pack,
//    pre-transposed bf16 K/V in ws, XCD swizzle.

typedef short short8 __attribute__((ext_vector_type(8)));
typedef float f32x16 __attribute__((ext_vector_type(16)));

#define MFMA32(a, b, c) __builtin_amdgcn_mfma_f32_32x32x16_bf16((a), (b), (c), 0, 0, 0)

#if __has_builtin(__builtin_amdgcn_exp2f)
#define EXP2(x) __builtin_amdgcn_exp2f(x)
#else
#define EXP2(x) exp2f(x)
#endif

constexpr int Dh  = 128;
constexpr int S_  = 2048;
constexpr int KVB = 64;
constexpr int NT  = S_ / KVB;          // 32 kv tiles
constexpr int WAVES = 8;
constexpr int QBLK  = 256;             // 8 waves x 32 q-rows

__device__ __forceinline__ short f2bf(float f) {
    union { float f; unsigned u; } x; x.f = f;
    unsigned r = x.u + 0x7fffu + ((x.u >> 16) & 1u);   // RNE
    return (short)(r >> 16);
}

__device__ __forceinline__ unsigned pkbf(float lo, float hi) {
    unsigned r;
    asm("v_cvt_pk_bf16_f32 %0, %1, %2" : "=v"(r) : "v"(lo), "v"(hi));
    return r;
}

// v_permlane32_swap_b32: a.row1 <-> b.row0  (rows = lane<32 / lane>=32)
__device__ __forceinline__ void pswap(unsigned &a, unsigned &b) {
    asm("v_permlane32_swap_b32 %0, %1" : "+v"(a), "+v"(b));
}

__device__ __forceinline__ void gload16(const void* g, void* l) {
    __builtin_amdgcn_global_load_lds(
        (const __attribute__((address_space(1))) unsigned int*)g,
        (__attribute__((address_space(3))) unsigned int*)l, 16, 0, 0);
}

// ---------------- merged pre-pass: K -> bf16 swizzled; V -> bf16 transposed
// blocks [0, 4096): Kz[row][blk] = K[row][blk ^ (row&15)]   (16B blocks)
// blocks [4096, 6144): Vt[bh][seg][d][64], 16B block j holds s-block j^(d&7)
__global__ __launch_bounds__(256) void prep_kv(const float* __restrict__ K,
                                               const float* __restrict__ V,
                                               short* __restrict__ Kz,
                                               short* __restrict__ Vt) {
    __shared__ short tr[64][72];
    if (blockIdx.x < 4096) {
        int idx = blockIdx.x * 256 + threadIdx.x;     // one 16B out block
        int b   = idx & 15;
        int s   = (idx >> 4) & (S_ - 1);
        int sb  = b ^ (s & 15);
        const float* src = K + (size_t)(idx >> 4) * Dh + sb * 8;
        float4 f0 = ((const float4*)src)[0];
        float4 f1 = ((const float4*)src)[1];
        short8 o;
        o[0] = f2bf(f0.x); o[1] = f2bf(f0.y); o[2] = f2bf(f0.z); o[3] = f2bf(f0.w);
        o[4] = f2bf(f1.x); o[5] = f2bf(f1.y); o[6] = f2bf(f1.z); o[7] = f2bf(f1.w);
        *(short8*)(Kz + (size_t)idx * 8) = o;
    } else {
        int bid = blockIdx.x - 4096;
        int dg = bid & 1, seg = (bid >> 1) & 31, bh = bid >> 6;
        int t = threadIdx.x;
        int s = t >> 2, d0 = (t & 3) * 16;
        const float* src = V + (size_t)(bh * S_ + seg * 64 + s) * Dh + dg * 64 + d0;
        #pragma unroll
        for (int i = 0; i < 16; i += 4) {
            float4 f = *(const float4*)(src + i);
            tr[d0 + i + 0][s] = f2bf(f.x); tr[d0 + i + 1][s] = f2bf(f.y);
            tr[d0 + i + 2][s] = f2bf(f.z); tr[d0 + i + 3][s] = f2bf(f.w);
        }
        __syncthreads();
        int d = t >> 2, j0 = (t & 3) * 2;
        size_t ob = ((size_t)(bh * 32 + seg) * 128 + dg * 64 + d) * 64;
        #pragma unroll
        for (int jj = 0; jj < 2; ++jj) {
            int j = j0 + jj;
            int sj = (j ^ (d & 7)) * 8;
            short8 val = *(const short8*)&tr[d][sj];
            *(short8*)(Vt + ob + j * 8) = val;
        }
    }
}

// ---------------- main flash kernel (8-wave, interleaved SM/PV) ------------
__global__ __launch_bounds__(512, 1)
void mea_fwd8(const float* __restrict__ Qg, const short* __restrict__ Kz,
              const short* __restrict__ Vt, float* __restrict__ Og, int nqt) {
    __shared__ __align__(16) short kbuf[3][KVB * Dh];   // 3 x 16 KB
    __shared__ __align__(16) short vbuf[3][Dh * KVB];   // 3 x 16 KB
    __shared__ float bc_lds[WAVES][32];                  // rare-path broadcast

    const int bid = blockIdx.x;
    const int cpx = (int)gridDim.x >> 3;
    const int swz = (bid & 7) * cpx + (bid >> 3);
    const int qt  = swz % nqt;
    const int bh  = swz / nqt;

    const int tid  = threadIdx.x;
    const int w    = tid >> 6;
    const int lane = tid & 63;
    const int l31  = lane & 31;
    const int hi   = lane >> 5;

    const size_t base = (size_t)bh * S_ * Dh;
    const int    qrow = qt * QBLK + w * 32 + l31;
    const float  QSC  = 0.08838834764831845f * 1.4426950408889634f; // scale*log2e

    // Q B-frags, pre-scaled
    short8 qf[8];
    {
        const float* qp = Qg + base + (size_t)qrow * Dh;
        #pragma unroll
        for (int kc = 0; kc < 8; ++kc) {
            const float4 f0 = *(const float4*)(qp + kc * 16 + hi * 8);
            const float4 f1 = *(const float4*)(qp + kc * 16 + hi * 8 + 4);
            short8 a;
            a[0] = f2bf(f0.x * QSC); a[1] = f2bf(f0.y * QSC);
            a[2] = f2bf(f0.z * QSC); a[3] = f2bf(f0.w * QSC);
            a[4] = f2bf(f1.x * QSC); a[5] = f2bf(f1.y * QSC);
            a[6] = f2bf(f1.z * QSC); a[7] = f2bf(f1.w * QSC);
            qf[kc] = a;
        }
    }

    f32x16 oacc[4];
    #pragma unroll
    for (int dt = 0; dt < 4; ++dt)
        #pragma unroll
        for (int r = 0; r < 16; ++r) oacc[dt][r] = 0.f;
    float mrun = -1e30f, lpart = 0.f;

    const short* kt0 = Kz + base;
    const short* vt0 = Vt + base;

    short *kA = kbuf[0], *kB = kbuf[1], *kC = kbuf[2];
    short *vA = vbuf[0], *vB = vbuf[1], *vC = vbuf[2];

    auto STAGE = [&](short* kl, short* vl, int t) {
        const short* ks = kt0 + (size_t)t * (KVB * Dh);
        const short* vs = vt0 + (size_t)t * (Dh * KVB);
        #pragma unroll
        for (int i = 0; i < 2; ++i) {
            const int ou = (i * 8 + w) * 512;
            gload16(ks + ou + lane * 8, kl + ou);
            gload16(vs + ou + lane * 8, vl + ou);
        }
    };

    auto QKSTEP = [&](const short* kl, f32x16& A, f32x16& B) {
        #pragma unroll
        for (int r = 0; r < 16; ++r) { A[r] = 0.f; B[r] = 0.f; }
        __builtin_amdgcn_s_setprio(1);
        #pragma unroll
        for (int kc = 0; kc < 8; ++kc) {
            const int go = (((kc * 2 + hi) ^ (l31 & 15)) * 8);
            const short8 a0 = *(const short8*)&kl[l31 * Dh + go];
            const short8 a1 = *(const short8*)&kl[(32 + l31) * Dh + go];
            A = MFMA32(a0, qf[kc], A);
            B = MFMA32(a1, qf[kc], B);
        }
        __builtin_amdgcn_s_setprio(0);
    };

    // one PV quadrant: 4 ds_read + 4 MFMA into od (static dt at call sites)
    auto PVQ = [&](const short* vl, const short8* pf, f32x16& od, int dt) {
        __builtin_amdgcn_s_setprio(1);
        #pragma unroll
        for (int ks = 0; ks < 4; ++ks) {
            const short8 bv = *(const short8*)
                &vl[(dt * 32 + l31) * KVB + (((ks * 2 + hi) ^ (l31 & 7)) * 8)];
            od = MFMA32(pf[ks], bv, od);
        }
        __builtin_amdgcn_s_setprio(0);
    };

    // exp2 half of an S-tile in place, accumulate sum (static h)
    auto EXPH = [&](f32x16& S, int h, float& sum) {
        #pragma unroll
        for (int r = 0; r < 8; ++r) {
            const float p = EXP2(S[h * 8 + r] - mrun);
            S[h * 8 + r] = p;
            sum += p;
        }
    };

    // pack fully-exp'd S-tile -> two PV A-frags
    auto PACKH = [&](const f32x16& S, short8* pf2) {
        #pragma unroll
        for (int kk = 0; kk < 2; ++kk) {
            unsigned a0 = pkbf(S[kk * 8 + 0], S[kk * 8 + 1]);
            unsigned a1 = pkbf(S[kk * 8 + 2], S[kk * 8 + 3]);
            unsigned b0 = pkbf(S[kk * 8 + 4], S[kk * 8 + 5]);
            unsigned b1 = pkbf(S[kk * 8 + 6], S[kk * 8 + 7]);
            pswap(a0, b0); pswap(a1, b1);
            unsigned wd[4] = {a0, a1, b0, b1};
            pf2[kk] = *(const short8*)wd;
        }
    };

    auto RESCALE = [&](float mxl) {
        float mo   = fmaxf(mxl, __shfl_xor(mxl, 32));
        float mnew = fmaxf(mrun, mo);
        float rc   = EXP2(mrun - mnew);
        mrun = mnew;
        lpart *= rc;
        if (!hi) bc_lds[w][l31] = rc;
        #pragma unroll
        for (int m = 0; m < 4; ++m) {
            const float4 rcv = *(const float4*)&bc_lds[w][m * 8 + 4 * hi];
            #pragma unroll
            for (int t2 = 0; t2 < 4; ++t2) {
                const float f = (&rcv.x)[t2];
                #pragma unroll
                for (int dt = 0; dt < 4; ++dt) oacc[dt][m * 4 + t2] *= f;
            }
        }
    };

    // BODY(t): stage(t+2); QK(t+1); interleave PV(t) with exp/pack(t+1)
    auto BODY = [&](int t, const short8* pfC, short8* pfN) {
        if (t + 2 < NT) STAGE(kC, vC, t + 2);
        f32x16 SA, SB;
        QKSTEP(kB, SA, SB);
        float mxl = SA[0];
        #pragma unroll
        for (int r = 1; r < 16; ++r) mxl = fmaxf(mxl, SA[r]);
        #pragma unroll
        for (int r = 0; r < 16; ++r) mxl = fmaxf(mxl, SB[r]);
        float sum = 0.f;
        if (!__any(mxl > mrun + 8.0f)) {
            // common path: mrun unchanged -> exp/pack(t+1) interleaves with PV(t)
            PVQ(vA, pfC, oacc[0], 0); EXPH(SA, 0, sum);
            PVQ(vA, pfC, oacc[1], 1); EXPH(SA, 1, sum); PACKH(SA, pfN);
            PVQ(vA, pfC, oacc[2], 2); EXPH(SB, 0, sum);
            PVQ(vA, pfC, oacc[3], 3); EXPH(SB, 1, sum); PACKH(SB, pfN + 2);
        } else {
            // rare path: PV must finish before oacc rescale
            PVQ(vA, pfC, oacc[0], 0); PVQ(vA, pfC, oacc[1], 1);
            PVQ(vA, pfC, oacc[2], 2); PVQ(vA, pfC, oacc[3], 3);
            RESCALE(mxl);
            EXPH(SA, 0, sum); EXPH(SA, 1, sum); PACKH(SA, pfN);
            EXPH(SB, 0, sum); EXPH(SB, 1, sum); PACKH(SB, pfN + 2);
        }
        lpart += sum;
        __syncthreads();
        short* tk = kA; kA = kB; kB = kC; kC = tk;
        short* tv = vA; vA = vB; vB = vC; vC = tv;
    };

    // ---- prologue: stage 0,1; QK(0); softmax+pack(0) -> pfA ----
    STAGE(kA, vA, 0);
    STAGE(kB, vB, 1);
    __syncthreads();
    short8 pfA[4], pfB[4];
    {
        f32x16 SA, SB;
        QKSTEP(kA, SA, SB);
        float mxl = SA[0];
        #pragma unroll
        for (int r = 1; r < 16; ++r) mxl = fmaxf(mxl, SA[r]);
        #pragma unroll
        for (int r = 0; r < 16; ++r) mxl = fmaxf(mxl, SB[r]);
        RESCALE(mxl);           // first tile: always establishes mrun
        float sum = 0.f;
        EXPH(SA, 0, sum); EXPH(SA, 1, sum); PACKH(SA, pfA);
        EXPH(SB, 0, sum); EXPH(SB, 1, sum); PACKH(SB, pfA + 2);
        lpart += sum;
    }

    // ---- main loop: t = 0..30 (31 bodies), then tail PV(31) ----
    #pragma unroll 1
    for (int kk = 0; kk < 15; ++kk) {
        BODY(2 * kk,     pfA, pfB);
        BODY(2 * kk + 1, pfB, pfA);
    }
    BODY(30, pfA, pfB);
    PVQ(vA, pfB, oacc[0], 0); PVQ(vA, pfB, oacc[1], 1);
    PVQ(vA, pfB, oacc[2], 2); PVQ(vA, pfB, oacc[3], 3);

    // ---- epilogue ----
    {
        const float tot = lpart + __shfl_xor(lpart, 32);
        if (!hi) bc_lds[w][l31] = 1.0f / tot;
    }
    float* op = Og + base;
    #pragma unroll
    for (int m = 0; m < 4; ++m) {
        const float4 li = *(const float4*)&bc_lds[w][m * 8 + 4 * hi];
        #pragma unroll
        for (int t2 = 0; t2 < 4; ++t2) {
            const int row  = m * 8 + 4 * hi + t2;
            const float lf = (&li.x)[t2];
            #pragma unroll
            for (int dt = 0; dt < 4; ++dt)
                op[(size_t)(qt * QBLK + w * 32 + row) * Dh + dt * 32 + l31]
                    = oacc[dt][m * 4 + t2] * lf;
        }
    }
}

// ---------------- fallback (no-ws path) ------------------------------------
typedef float f32x4 __attribute__((ext_vector_type(4)));
#define MFMA16(a, b, c) __builtin_amdgcn_mfma_f32_16x16x32_bf16((a), (b), (c), 0, 0, 0)
constexpr int FKVB = 32;
constexpr int FKP  = 136;
constexpr int FVP  = 40;
constexpr int FPP  = 40;

__global__ __launch_bounds__(256, 2)
void mea_fwd_fb(const float* __restrict__ Qg, const float* __restrict__ Kg,
                const float* __restrict__ Vg, float* __restrict__ Og,
                int S, int nqt) {
    __shared__ __align__(16) short k_lds[FKVB][FKP];
    __shared__ __align__(16) short vT_lds[Dh][FVP];
    __shared__ __align__(16) short p_lds[4][16][FPP];

    const int qt = blockIdx.x % nqt;
    const int bh = blockIdx.x / nqt;
    const int tid = threadIdx.x;
    const int w = tid >> 6, lane = tid & 63;
    const int lr = lane & 15, lg = lane >> 4;
    const size_t base = (size_t)bh * S * Dh;
    const int qrow0 = qt * 64 + w * 16;
    const float scale = 0.08838834764831845f;

    short8 qf[4];
    {
        const float* qp = Qg + base + (size_t)(qrow0 + lr) * Dh;
        #pragma unroll
        for (int kc = 0; kc < 4; ++kc) {
            const float4 f0 = *(const float4*)(qp + kc * 32 + lg * 8);
            const float4 f1 = *(const float4*)(qp + kc * 32 + lg * 8 + 4);
            short8 a;
            a[0] = f2bf(f0.x); a[1] = f2bf(f0.y); a[2] = f2bf(f0.z); a[3] = f2bf(f0.w);
            a[4] = f2bf(f1.x); a[5] = f2bf(f1.y); a[6] = f2bf(f1.z); a[7] = f2bf(f1.w);
            qf[kc] = a;
        }
    }
    f32x4 oacc[8];
    #pragma unroll
    for (int dt = 0; dt < 8; ++dt) oacc[dt] = (f32x4){0.f, 0.f, 0.f, 0.f};
    float mrun[4] = {-1e30f, -1e30f, -1e30f, -1e30f};
    float lrun[4] = {0.f, 0.f, 0.f, 0.f};
    const int sr = tid >> 3, sc = (tid & 7) * 16;

    for (int kv0 = 0; kv0 < S; kv0 += FKVB) {
        {
            const float* kp = Kg + base + (size_t)(kv0 + sr) * Dh + sc;
            const float* vp = Vg + base + (size_t)(kv0 + sr) * Dh + sc;
            short8 pk0, pk1;
            float4 f0 = ((const float4*)kp)[0], f1 = ((const float4*)kp)[1];
            float4 f2 = ((const float4*)kp)[2], f3 = ((const float4*)kp)[3];
            pk0[0] = f2bf(f0.x); pk0[1] = f2bf(f0.y); pk0[2] = f2bf(f0.z); pk0[3] = f2bf(f0.w);
            pk0[4] = f2bf(f1.x); pk0[5] = f2bf(f1.y); pk0[6] = f2bf(f1.z); pk0[7] = f2bf(f1.w);
            pk1[0] = f2bf(f2.x); pk1[1] = f2bf(f2.y); pk1[2] = f2bf(f2.z); pk1[3] = f2bf(f2.w);
            pk1[4] = f2bf(f3.x); pk1[5] = f2bf(f3.y); pk1[6] = f2bf(f3.z); pk1[7] = f2bf(f3.w);
            *(short8*)&k_lds[sr][sc] = pk0;
            *(short8*)&k_lds[sr][sc + 8] = pk1;
            #pragma unroll
            for (int i = 0; i < 4; ++i) {
                float4 f = ((const float4*)vp)[i];
                vT_lds[sc + 4 * i + 0][sr] = f2bf(f.x);
                vT_lds[sc + 4 * i + 1][sr] = f2bf(f.y);
                vT_lds[sc + 4 * i + 2][sr] = f2bf(f.z);
                vT_lds[sc + 4 * i + 3][sr] = f2bf(f.w);
            }
        }
        __syncthreads();
        f32x4 s0 = (f32x4){0.f,0.f,0.f,0.f}, s1 = (f32x4){0.f,0.f,0.f,0.f};
        #pragma unroll
        for (int kc = 0; kc < 4; ++kc) {
            short8 b0 = *(const short8*)&k_lds[lr][kc * 32 + lg * 8];
            short8 b1 = *(const short8*)&k_lds[16 + lr][kc * 32 + lg * 8];
            s0 = MFMA16(qf[kc], b0, s0);
            s1 = MFMA16(qf[kc], b1, s1);
        }
        float resc[4];
        #pragma unroll
        for (int r = 0; r < 4; ++r) {
            float mxv = fmaxf(s0[r], s1[r]);
            #pragma unroll
            for (int m = 1; m < 16; m <<= 1) mxv = fmaxf(mxv, __shfl_xor(mxv, m));
            float mnew = fmaxf(mrun[r], mxv * scale);
            float rc = __expf(mrun[r] - mnew);
            mrun[r] = mnew;
            float p0 = __expf(s0[r] * scale - mnew);
            float p1 = __expf(s1[r] * scale - mnew);
            float rs = p0 + p1;
            #pragma unroll
            for (int m = 1; m < 16; m <<= 1) rs += __shfl_xor(rs, m);
            lrun[r] = lrun[r] * rc + rs;
            resc[r] = rc;
            p_lds[w][lg * 4 + r][lr] = f2bf(p0);
            p_lds[w][lg * 4 + r][16 + lr] = f2bf(p1);
        }
        #pragma unroll
        for (int dt = 0; dt < 8; ++dt) {
            f32x4 o = oacc[dt];
            o[0] *= resc[0]; o[1] *= resc[1]; o[2] *= resc[2]; o[3] *= resc[3];
            oacc[dt] = o;
        }
        short8 ap = *(const short8*)&p_lds[w][lr][lg * 8];
        #pragma unroll
        for (int dt = 0; dt < 8; ++dt) {
            short8 bv = *(const short8*)&vT_lds[dt * 16 + lr][lg * 8];
            oacc[dt] = MFMA16(ap, bv, oacc[dt]);
        }
        __syncthreads();
    }
    float inv[4];
    #pragma unroll
    for (int r = 0; r < 4; ++r) inv[r] = 1.0f / lrun[r];
    float* op = Og + base;
    #pragma unroll
    for (int dt = 0; dt < 8; ++dt)
        #pragma unroll
        for (int r = 0; r < 4; ++r)
            op[(size_t)(qrow0 + lg * 4 + r) * Dh + dt * 16 + lr] = oacc[dt][r] * inv[r];
}

extern "C" void kernel_launch(void* const* d_in, const int* in_sizes, int n_in,
                              void* d_out, int out_size, void* d_ws, size_t ws_size,
                              hipStream_t stream) {
    const float* q = (const float*)d_in[0];
    const float* k = (const float*)d_in[1];
    const float* v = (const float*)d_in[2];
    float* o = (float*)d_out;

    const int BH  = in_sizes[0] / (S_ * Dh);     // 32
    const int nqt = S_ / QBLK;                    // 8

    const size_t kz_bytes = (size_t)BH * S_ * Dh * sizeof(short);   // 16.78 MB
    const size_t need = 2 * kz_bytes;

    if (ws_size >= need) {
        short* Kz = (short*)d_ws;
        short* Vt = (short*)((char*)d_ws + kz_bytes);
        hipLaunchKernelGGL(prep_kv, dim3(4096 + BH * (S_ / 64) * 2), dim3(256),
                           0, stream, k, v, Kz, Vt);
        hipLaunchKernelGGL(mea_fwd8, dim3(BH * nqt), dim3(512), 0, stream,
                           q, Kz, Vt, o, nqt);
    } else {
        hipLaunchKernelGGL(mea_fwd_fb, dim3(BH * (S_ / 64)), dim3(256), 0, stream,
                           q, k, v, o, S_, S_ / 64);
    }
}

// Round 9
// 99.743 us; speedup vs baseline: 1.3597x; 1.3597x over previous
//
#include <hip/hip_runtime.h>
#include <hip/hip_bf16.h>

// MemoryEfficientAttention round 9: V reads moved off the LDS pipe.
//  - Model: at 91us the CU-wide LDS pipe (~3100 cy/tile: 8 waves x 32KB
//    ds_read_b128 @ ~85 B/cy) is the largest consumer; all waves read the
//    SAME K/V tiles. Fix: K stays in LDS (halved traffic), V is read directly
//    from global in a fragment-ordered layout (each load = base + lane*16B,
//    perfectly coalesced, L1-broadcast across the 8 waves) -> V traffic runs
//    on the TA/L1 pipe in parallel with LDS + MFMA.
//  - V loads double-buffered in statically-named regs (rule #20 safe);
//    dt0 issued before softmax to hide L1/L2 latency.
//  - Round-6 skeleton otherwise: swapped-QK 32x32, 8 waves x 32 q, grid 256,
//    2-phase K double-buffer, permlane32_swap pack, defer-max, XCD swizzle.

typedef short short8 __attribute__((ext_vector_type(8)));
typedef float f32x16 __attribute__((ext_vector_type(16)));

#define MFMA32(a, b, c) __builtin_amdgcn_mfma_f32_32x32x16_bf16((a), (b), (c), 0, 0, 0)

#if __has_builtin(__builtin_amdgcn_exp2f)
#define EXP2(x) __builtin_amdgcn_exp2f(x)
#else
#define EXP2(x) exp2f(x)
#endif

constexpr int Dh  = 128;
constexpr int S_  = 2048;
constexpr int KVB = 64;
constexpr int NT  = S_ / KVB;          // 32 kv tiles
constexpr int WAVES = 8;
constexpr int QBLK  = 256;             // 8 waves x 32 q-rows

__device__ __forceinline__ short f2bf(float f) {
    union { float f; unsigned u; } x; x.f = f;
    unsigned r = x.u + 0x7fffu + ((x.u >> 16) & 1u);   // RNE
    return (short)(r >> 16);
}

__device__ __forceinline__ unsigned pkbf(float lo, float hi) {
    unsigned r;
    asm("v_cvt_pk_bf16_f32 %0, %1, %2" : "=v"(r) : "v"(lo), "v"(hi));
    return r;
}

// v_permlane32_swap_b32: a.row1 <-> b.row0  (rows = lane<32 / lane>=32)
__device__ __forceinline__ void pswap(unsigned &a, unsigned &b) {
    asm("v_permlane32_swap_b32 %0, %1" : "+v"(a), "+v"(b));
}

__device__ __forceinline__ void gload16(const void* g, void* l) {
    __builtin_amdgcn_global_load_lds(
        (const __attribute__((address_space(1))) unsigned int*)g,
        (__attribute__((address_space(3))) unsigned int*)l, 16, 0, 0);
}

// ---------------- merged pre-pass -----------------------------------------
// blocks [0, 4096): Kz[row][blk] = K[row][blk ^ (row&15)]   (16B blocks)
// blocks [4096, 5120): Vt2[bh][seg][dt][ks][lane][8]:
//   element (dt,ks,lane,e) = V[bh][seg*64 + ks*16 + (lane>>5)*8 + e]
//                             [dt*32 + (lane&31)]
//   -> a PV B-frag load is one contiguous 1KB wave read at base + lane*16B.
__global__ __launch_bounds__(256) void prep_kv(const float* __restrict__ K,
                                               const float* __restrict__ V,
                                               short* __restrict__ Kz,
                                               short* __restrict__ Vt) {
    __shared__ short tr[64][132];
    if (blockIdx.x < 4096) {
        int idx = blockIdx.x * 256 + threadIdx.x;     // one 16B out block
        int b   = idx & 15;
        int s   = (idx >> 4) & (S_ - 1);
        int sb  = b ^ (s & 15);
        const float* src = K + (size_t)(idx >> 4) * Dh + sb * 8;
        float4 f0 = ((const float4*)src)[0];
        float4 f1 = ((const float4*)src)[1];
        short8 o;
        o[0] = f2bf(f0.x); o[1] = f2bf(f0.y); o[2] = f2bf(f0.z); o[3] = f2bf(f0.w);
        o[4] = f2bf(f1.x); o[5] = f2bf(f1.y); o[6] = f2bf(f1.z); o[7] = f2bf(f1.w);
        *(short8*)(Kz + (size_t)idx * 8) = o;
    } else {
        int bid = blockIdx.x - 4096;      // 0..1023
        int seg = bid & 31, bh = bid >> 5;
        int t = threadIdx.x;
        // load+convert tile [64 kv][128 d] into LDS (coalesced)
        {
            const int s = t >> 2, d0 = (t & 3) * 32;
            const float* src = V + ((size_t)(bh * S_ + seg * 64 + s)) * Dh + d0;
            #pragma unroll
            for (int i = 0; i < 4; ++i) {
                float4 f0 = ((const float4*)src)[2 * i];
                float4 f1 = ((const float4*)src)[2 * i + 1];
                short8 o;
                o[0] = f2bf(f0.x); o[1] = f2bf(f0.y); o[2] = f2bf(f0.z); o[3] = f2bf(f0.w);
                o[4] = f2bf(f1.x); o[5] = f2bf(f1.y); o[6] = f2bf(f1.z); o[7] = f2bf(f1.w);
                *(short8*)&tr[s][d0 + i * 8] = o;
            }
        }
        __syncthreads();
        // gather into fragment order
        short* outb = Vt + ((size_t)(bh * 32 + seg)) * 8192;
        #pragma unroll
        for (int jj = 0; jj < 4; ++jj) {
            const int j   = (t << 2) | jj;      // 0..1023
            const int dt  = j >> 8;
            const int ks  = (j >> 6) & 3;
            const int ln  = j & 63;
            const int hi2 = ln >> 5, l31 = ln & 31;
            short8 o;
            #pragma unroll
            for (int e = 0; e < 8; ++e)
                o[e] = tr[ks * 16 + hi2 * 8 + e][dt * 32 + l31];
            *(short8*)(outb + (size_t)j * 8) = o;
        }
    }
}

// ---------------- main flash kernel ----------------------------------------
__global__ __launch_bounds__(512, 1)
void mea_fwd9(const float* __restrict__ Qg, const short* __restrict__ Kz,
              const short* __restrict__ Vt, float* __restrict__ Og, int nqt) {
    __shared__ __align__(16) short k0[KVB * Dh], k1[KVB * Dh];   // 2 x 16 KB
    __shared__ float bc_lds[WAVES][32];

    const int bid = blockIdx.x;
    const int cpx = (int)gridDim.x >> 3;
    const int swz = (bid & 7) * cpx + (bid >> 3);
    const int qt  = swz % nqt;
    const int bh  = swz / nqt;

    const int tid  = threadIdx.x;
    const int w    = tid >> 6;
    const int lane = tid & 63;
    const int l31  = lane & 31;
    const int hi   = lane >> 5;

    const size_t base = (size_t)bh * S_ * Dh;
    const int    qrow = qt * QBLK + w * 32 + l31;
    const float  QSC  = 0.08838834764831845f * 1.4426950408889634f; // scale*log2e

    // Q B-frags, pre-scaled
    short8 qf[8];
    {
        const float* qp = Qg + base + (size_t)qrow * Dh;
        #pragma unroll
        for (int kc = 0; kc < 8; ++kc) {
            const float4 f0 = *(const float4*)(qp + kc * 16 + hi * 8);
            const float4 f1 = *(const float4*)(qp + kc * 16 + hi * 8 + 4);
            short8 a;
            a[0] = f2bf(f0.x * QSC); a[1] = f2bf(f0.y * QSC);
            a[2] = f2bf(f0.z * QSC); a[3] = f2bf(f0.w * QSC);
            a[4] = f2bf(f1.x * QSC); a[5] = f2bf(f1.y * QSC);
            a[6] = f2bf(f1.z * QSC); a[7] = f2bf(f1.w * QSC);
            qf[kc] = a;
        }
    }

    f32x16 oacc[4];
    #pragma unroll
    for (int dt = 0; dt < 4; ++dt)
        #pragma unroll
        for (int r = 0; r < 16; ++r) oacc[dt][r] = 0.f;
    float mrun = -1e30f, lpart = 0.f;

    const short* kt0 = Kz + base;              // K tiles [64 kv][128 d]
    const short* vt0 = Vt + base;              // V frag tiles, 8192 shorts each

    auto STAGE = [&](short* kl, int t) {
        const short* ks = kt0 + (size_t)t * (KVB * Dh);
        #pragma unroll
        for (int i = 0; i < 2; ++i) {
            const int ou = (i * 8 + w) * 512;
            gload16(ks + ou + lane * 8, kl + ou);
        }
    };

    // V fragment load: contiguous 1KB per (dt,ks), lane*16B
#define VLD(vg, dt, ks) (*(const short8*)((vg) + (((dt) * 4 + (ks)) * 64 + lane) * 8))

    auto COMPUTE = [&](const short* kl, int t) {
        const short* vg = vt0 + (size_t)t * 8192;

        // ---- S^T = K Q ----
        f32x16 SA, SB;
        #pragma unroll
        for (int r = 0; r < 16; ++r) { SA[r] = 0.f; SB[r] = 0.f; }
        __builtin_amdgcn_s_setprio(1);
        #pragma unroll
        for (int kc = 0; kc < 8; ++kc) {
            const int go = (((kc * 2 + hi) ^ (l31 & 15)) * 8);
            const short8 a0 = *(const short8*)&kl[l31 * Dh + go];
            const short8 a1 = *(const short8*)&kl[(32 + l31) * Dh + go];
            SA = MFMA32(a0, qf[kc], SA);
            SB = MFMA32(a1, qf[kc], SB);
        }
        __builtin_amdgcn_s_setprio(0);

        // ---- issue V dt0 loads early (latency hides under softmax) ----
        short8 x0 = VLD(vg, 0, 0), x1 = VLD(vg, 0, 1);
        short8 x2 = VLD(vg, 0, 2), x3 = VLD(vg, 0, 3);

        // ---- lane-local softmax, defer-max THR=8 ----
        float mxl = SA[0];
        #pragma unroll
        for (int r = 1; r < 16; ++r) mxl = fmaxf(mxl, SA[r]);
        #pragma unroll
        for (int r = 0; r < 16; ++r) mxl = fmaxf(mxl, SB[r]);
        if (__any(mxl > mrun + 8.0f)) {
            float mo   = fmaxf(mxl, __shfl_xor(mxl, 32));
            float mnew = fmaxf(mrun, mo);
            float rc   = EXP2(mrun - mnew);
            mrun = mnew;
            lpart *= rc;
            if (!hi) bc_lds[w][l31] = rc;
            #pragma unroll
            for (int m = 0; m < 4; ++m) {
                const float4 rcv = *(const float4*)&bc_lds[w][m * 8 + 4 * hi];
                #pragma unroll
                for (int t2 = 0; t2 < 4; ++t2) {
                    const float f = (&rcv.x)[t2];
                    #pragma unroll
                    for (int dt = 0; dt < 4; ++dt) oacc[dt][m * 4 + t2] *= f;
                }
            }
        }

        // ---- P = exp2(S - m) in place, row sums ----
        float sum = 0.f;
        #pragma unroll
        for (int r = 0; r < 16; ++r) { SA[r] = EXP2(SA[r] - mrun); sum += SA[r]; }
        #pragma unroll
        for (int r = 0; r < 16; ++r) { SB[r] = EXP2(SB[r] - mrun); sum += SB[r]; }
        lpart += sum;

        // ---- pack to PV A-frags: 16 cvt_pk + 8 permlane32_swap ----
        short8 pf[4];
        #pragma unroll
        for (int kk = 0; kk < 2; ++kk) {
            unsigned a0 = pkbf(SA[kk * 8 + 0], SA[kk * 8 + 1]);
            unsigned a1 = pkbf(SA[kk * 8 + 2], SA[kk * 8 + 3]);
            unsigned b0 = pkbf(SA[kk * 8 + 4], SA[kk * 8 + 5]);
            unsigned b1 = pkbf(SA[kk * 8 + 6], SA[kk * 8 + 7]);
            pswap(a0, b0); pswap(a1, b1);
            unsigned wd[4] = {a0, a1, b0, b1};
            pf[kk] = *(const short8*)wd;
        }
        #pragma unroll
        for (int kk = 0; kk < 2; ++kk) {
            unsigned a0 = pkbf(SB[kk * 8 + 0], SB[kk * 8 + 1]);
            unsigned a1 = pkbf(SB[kk * 8 + 2], SB[kk * 8 + 3]);
            unsigned b0 = pkbf(SB[kk * 8 + 4], SB[kk * 8 + 5]);
            unsigned b1 = pkbf(SB[kk * 8 + 6], SB[kk * 8 + 7]);
            pswap(a0, b0); pswap(a1, b1);
            unsigned wd[4] = {a0, a1, b0, b1};
            pf[2 + kk] = *(const short8*)wd;
        }

        // ---- O += P V : per d-tile, double-buffered V regs ----
        short8 w0 = VLD(vg, 1, 0), w1 = VLD(vg, 1, 1);
        short8 w2 = VLD(vg, 1, 2), w3 = VLD(vg, 1, 3);
        __builtin_amdgcn_s_setprio(1);
        oacc[0] = MFMA32(pf[0], x0, oacc[0]); oacc[0] = MFMA32(pf[1], x1, oacc[0]);
        oacc[0] = MFMA32(pf[2], x2, oacc[0]); oacc[0] = MFMA32(pf[3], x3, oacc[0]);
        __builtin_amdgcn_s_setprio(0);
        x0 = VLD(vg, 2, 0); x1 = VLD(vg, 2, 1);
        x2 = VLD(vg, 2, 2); x3 = VLD(vg, 2, 3);
        __builtin_amdgcn_s_setprio(1);
        oacc[1] = MFMA32(pf[0], w0, oacc[1]); oacc[1] = MFMA32(pf[1], w1, oacc[1]);
        oacc[1] = MFMA32(pf[2], w2, oacc[1]); oacc[1] = MFMA32(pf[3], w3, oacc[1]);
        __builtin_amdgcn_s_setprio(0);
        w0 = VLD(vg, 3, 0); w1 = VLD(vg, 3, 1);
        w2 = VLD(vg, 3, 2); w3 = VLD(vg, 3, 3);
        __builtin_amdgcn_s_setprio(1);
        oacc[2] = MFMA32(pf[0], x0, oacc[2]); oacc[2] = MFMA32(pf[1], x1, oacc[2]);
        oacc[2] = MFMA32(pf[2], x2, oacc[2]); oacc[2] = MFMA32(pf[3], x3, oacc[2]);
        oacc[3] = MFMA32(pf[0], w0, oacc[3]); oacc[3] = MFMA32(pf[1], w1, oacc[3]);
        oacc[3] = MFMA32(pf[2], w2, oacc[3]); oacc[3] = MFMA32(pf[3], w3, oacc[3]);
        __builtin_amdgcn_s_setprio(0);
    };

    // ---- 2-phase pipeline over K staging; V is global-direct ----
    STAGE(k0, 0);
    __syncthreads();
    #pragma unroll 1
    for (int t = 0; t < NT; t += 2) {
        STAGE(k1, t + 1);
        COMPUTE(k0, t);
        __syncthreads();
        if (t + 2 < NT) STAGE(k0, t + 2);
        COMPUTE(k1, t + 1);
        __syncthreads();
    }

    // ---- epilogue ----
    {
        const float tot = lpart + __shfl_xor(lpart, 32);
        if (!hi) bc_lds[w][l31] = 1.0f / tot;
    }
    float* op = Og + base;
    #pragma unroll
    for (int m = 0; m < 4; ++m) {
        const float4 li = *(const float4*)&bc_lds[w][m * 8 + 4 * hi];
        #pragma unroll
        for (int t2 = 0; t2 < 4; ++t2) {
            const int row  = m * 8 + 4 * hi + t2;
            const float lf = (&li.x)[t2];
            #pragma unroll
            for (int dt = 0; dt < 4; ++dt)
                op[(size_t)(qt * QBLK + w * 32 + row) * Dh + dt * 32 + l31]
                    = oacc[dt][m * 4 + t2] * lf;
        }
    }
#undef VLD
}

// ---------------- fallback (no-ws path) ------------------------------------
typedef float f32x4 __attribute__((ext_vector_type(4)));
#define MFMA16(a, b, c) __builtin_amdgcn_mfma_f32_16x16x32_bf16((a), (b), (c), 0, 0, 0)
constexpr int FKVB = 32;
constexpr int FKP  = 136;
constexpr int FVP  = 40;
constexpr int FPP  = 40;

__global__ __launch_bounds__(256, 2)
void mea_fwd_fb(const float* __restrict__ Qg, const float* __restrict__ Kg,
                const float* __restrict__ Vg, float* __restrict__ Og,
                int S, int nqt) {
    __shared__ __align__(16) short k_lds[FKVB][FKP];
    __shared__ __align__(16) short vT_lds[Dh][FVP];
    __shared__ __align__(16) short p_lds[4][16][FPP];

    const int qt = blockIdx.x % nqt;
    const int bh = blockIdx.x / nqt;
    const int tid = threadIdx.x;
    const int w = tid >> 6, lane = tid & 63;
    const int lr = lane & 15, lg = lane >> 4;
    const size_t base = (size_t)bh * S * Dh;
    const int qrow0 = qt * 64 + w * 16;
    const float scale = 0.08838834764831845f;

    short8 qf[4];
    {
        const float* qp = Qg + base + (size_t)(qrow0 + lr) * Dh;
        #pragma unroll
        for (int kc = 0; kc < 4; ++kc) {
            const float4 f0 = *(const float4*)(qp + kc * 32 + lg * 8);
            const float4 f1 = *(const float4*)(qp + kc * 32 + lg * 8 + 4);
            short8 a;
            a[0] = f2bf(f0.x); a[1] = f2bf(f0.y); a[2] = f2bf(f0.z); a[3] = f2bf(f0.w);
            a[4] = f2bf(f1.x); a[5] = f2bf(f1.y); a[6] = f2bf(f1.z); a[7] = f2bf(f1.w);
            qf[kc] = a;
        }
    }
    f32x4 oacc[8];
    #pragma unroll
    for (int dt = 0; dt < 8; ++dt) oacc[dt] = (f32x4){0.f, 0.f, 0.f, 0.f};
    float mrun[4] = {-1e30f, -1e30f, -1e30f, -1e30f};
    float lrun[4] = {0.f, 0.f, 0.f, 0.f};
    const int sr = tid >> 3, sc = (tid & 7) * 16;

    for (int kv0 = 0; kv0 < S; kv0 += FKVB) {
        {
            const float* kp = Kg + base + (size_t)(kv0 + sr) * Dh + sc;
            const float* vp = Vg + base + (size_t)(kv0 + sr) * Dh + sc;
            short8 pk0, pk1;
            float4 f0 = ((const float4*)kp)[0], f1 = ((const float4*)kp)[1];
            float4 f2 = ((const float4*)kp)[2], f3 = ((const float4*)kp)[3];
            pk0[0] = f2bf(f0.x); pk0[1] = f2bf(f0.y); pk0[2] = f2bf(f0.z); pk0[3] = f2bf(f0.w);
            pk0[4] = f2bf(f1.x); pk0[5] = f2bf(f1.y); pk0[6] = f2bf(f1.z); pk0[7] = f2bf(f1.w);
            pk1[0] = f2bf(f2.x); pk1[1] = f2bf(f2.y); pk1[2] = f2bf(f2.z); pk1[3] = f2bf(f2.w);
            pk1[4] = f2bf(f3.x); pk1[5] = f2bf(f3.y); pk1[6] = f2bf(f3.z); pk1[7] = f2bf(f3.w);
            *(short8*)&k_lds[sr][sc] = pk0;
            *(short8*)&k_lds[sr][sc + 8] = pk1;
            #pragma unroll
            for (int i = 0; i < 4; ++i) {
                float4 f = ((const float4*)vp)[i];
                vT_lds[sc + 4 * i + 0][sr] = f2bf(f.x);
                vT_lds[sc + 4 * i + 1][sr] = f2bf(f.y);
                vT_lds[sc + 4 * i + 2][sr] = f2bf(f.z);
                vT_lds[sc + 4 * i + 3][sr] = f2bf(f.w);
            }
        }
        __syncthreads();
        f32x4 s0 = (f32x4){0.f,0.f,0.f,0.f}, s1 = (f32x4){0.f,0.f,0.f,0.f};
        #pragma unroll
        for (int kc = 0; kc < 4; ++kc) {
            short8 b0 = *(const short8*)&k_lds[lr][kc * 32 + lg * 8];
            short8 b1 = *(const short8*)&k_lds[16 + lr][kc * 32 + lg * 8];
            s0 = MFMA16(qf[kc], b0, s0);
            s1 = MFMA16(qf[kc], b1, s1);
        }
        float resc[4];
        #pragma unroll
        for (int r = 0; r < 4; ++r) {
            float mxv = fmaxf(s0[r], s1[r]);
            #pragma unroll
            for (int m = 1; m < 16; m <<= 1) mxv = fmaxf(mxv, __shfl_xor(mxv, m));
            float mnew = fmaxf(mrun[r], mxv * scale);
            float rc = __expf(mrun[r] - mnew);
            mrun[r] = mnew;
            float p0 = __expf(s0[r] * scale - mnew);
            float p1 = __expf(s1[r] * scale - mnew);
            float rs = p0 + p1;
            #pragma unroll
            for (int m = 1; m < 16; m <<= 1) rs += __shfl_xor(rs, m);
            lrun[r] = lrun[r] * rc + rs;
            resc[r] = rc;
            p_lds[w][lg * 4 + r][lr] = f2bf(p0);
            p_lds[w][lg * 4 + r][16 + lr] = f2bf(p1);
        }
        #pragma unroll
        for (int dt = 0; dt < 8; ++dt) {
            f32x4 o = oacc[dt];
            o[0] *= resc[0]; o[1] *= resc[1]; o[2] *= resc[2]; o[3] *= resc[3];
            oacc[dt] = o;
        }
        short8 ap = *(const short8*)&p_lds[w][lr][lg * 8];
        #pragma unroll
        for (int dt = 0; dt < 8; ++dt) {
            short8 bv = *(const short8*)&vT_lds[dt * 16 + lr][lg * 8];
            oacc[dt] = MFMA16(ap, bv, oacc[dt]);
        }
        __syncthreads();
    }
    float inv[4];
    #pragma unroll
    for (int r = 0; r < 4; ++r) inv[r] = 1.0f / lrun[r];
    float* op = Og + base;
    #pragma unroll
    for (int dt = 0; dt < 8; ++dt)
        #pragma unroll
        for (int r = 0; r < 4; ++r)
            op[(size_t)(qrow0 + lg * 4 + r) * Dh + dt * 16 + lr] = oacc[dt][r] * inv[r];
}

extern "C" void kernel_launch(void* const* d_in, const int* in_sizes, int n_in,
                              void* d_out, int out_size, void* d_ws, size_t ws_size,
                              hipStream_t stream) {
    const float* q = (const float*)d_in[0];
    const float* k = (const float*)d_in[1];
    const float* v = (const float*)d_in[2];
    float* o = (float*)d_out;

    const int BH  = in_sizes[0] / (S_ * Dh);     // 32
    const int nqt = S_ / QBLK;                    // 8

    const size_t kz_bytes = (size_t)BH * S_ * Dh * sizeof(short);   // 16.78 MB
    const size_t need = 2 * kz_bytes;

    if (ws_size >= need) {
        short* Kz = (short*)d_ws;
        short* Vt = (short*)((char*)d_ws + kz_bytes);
        hipLaunchKernelGGL(prep_kv, dim3(4096 + BH * 32), dim3(256),
                           0, stream, k, v, Kz, Vt);
        hipLaunchKernelGGL(mea_fwd9, dim3(BH * nqt), dim3(512), 0, stream,
                           q, Kz, Vt, o, nqt);
    } else {
        hipLaunchKernelGGL(mea_fwd_fb, dim3(BH * (S_ / 64)), dim3(256), 0, stream,
                           q, k, v, o, S_, S_ / 64);
    }
}